// Round 4
// baseline (411.132 us; speedup 1.0000x reference)
//
#include <hip/hip_runtime.h>
#include <hip/hip_bf16.h>

#define NN 50000
#define NE 800000
#define DD 256
#define OO 32

typedef __attribute__((ext_vector_type(8))) short short8;
typedef __attribute__((ext_vector_type(4))) float float4v;

#define AS1 __attribute__((address_space(1)))
#define AS3 __attribute__((address_space(3)))

__device__ __forceinline__ float b2f(unsigned short u) {
    union { unsigned int i; float f; } x;
    x.i = ((unsigned int)u) << 16;
    return x.f;
}
__device__ __forceinline__ float lo16f(unsigned int u) {
    union { unsigned int i; float f; } x; x.i = u << 16; return x.f;
}
__device__ __forceinline__ float hi16f(unsigned int u) {
    union { unsigned int i; float f; } x; x.i = u & 0xFFFF0000u; return x.f;
}
__device__ __forceinline__ unsigned short f2b(float f) {
    union { float f; unsigned int i; } x;
    x.f = f;
    unsigned int r = x.i + 0x7FFFu + ((x.i >> 16) & 1u);  // RNE
    return (unsigned short)(r >> 16);
}

// ---------------------------------------------------------------------------
// CSR build
// ---------------------------------------------------------------------------
__global__ void count_kernel(const int* __restrict__ row, int* __restrict__ cnt, int E) {
    int e = blockIdx.x * blockDim.x + threadIdx.x;
    if (e < E) atomicAdd(&cnt[row[e]], 1);
}

__global__ __launch_bounds__(256) void block_sums(const int* __restrict__ cnt,
                                                  int* __restrict__ bsum, int N) {
    __shared__ int s[256];
    int idx = blockIdx.x * 256 + threadIdx.x;
    s[threadIdx.x] = (idx < N) ? cnt[idx] : 0;
    __syncthreads();
    for (int o = 128; o > 0; o >>= 1) {
        if (threadIdx.x < o) s[threadIdx.x] += s[threadIdx.x + o];
        __syncthreads();
    }
    if (threadIdx.x == 0) bsum[blockIdx.x] = s[0];
}

__global__ __launch_bounds__(256) void scan_bsums(const int* __restrict__ bsum,
                                                  int* __restrict__ bpre, int nb) {
    __shared__ int s[256];
    int t = threadIdx.x;
    int v0 = (t < nb) ? bsum[t] : 0;
    s[t] = v0;
    __syncthreads();
    for (int o = 1; o < 256; o <<= 1) {
        int v = (t >= o) ? s[t - o] : 0;
        __syncthreads();
        s[t] += v;
        __syncthreads();
    }
    if (t < nb) bpre[t] = s[t] - v0;  // exclusive prefix
}

__global__ __launch_bounds__(256) void fill_rowptr(const int* __restrict__ cnt,
                                                   const int* __restrict__ bpre,
                                                   int* __restrict__ row_ptr,
                                                   int* __restrict__ cursor,
                                                   float* __restrict__ dinv, int N, int E) {
    __shared__ int s[256];
    int t = threadIdx.x;
    int idx = blockIdx.x * 256 + t;
    int c = (idx < N) ? cnt[idx] : 0;
    s[t] = c;
    __syncthreads();
    for (int o = 1; o < 256; o <<= 1) {
        int v = (t >= o) ? s[t - o] : 0;
        __syncthreads();
        s[t] += v;
        __syncthreads();
    }
    int excl = bpre[blockIdx.x] + s[t] - c;
    if (idx < N) {
        row_ptr[idx] = excl;
        cursor[idx] = excl;
        dinv[idx] = rsqrtf((float)(c + 1));  // +1 self-loop
    }
    if (idx == N) row_ptr[N] = E;
}

__global__ void scatter_kernel(const int* __restrict__ row, const int* __restrict__ col,
                               int* __restrict__ cursor, int* __restrict__ csr_col, int E) {
    int e = blockIdx.x * blockDim.x + threadIdx.x;
    if (e < E) {
        int p = atomicAdd(&cursor[row[e]], 1);
        csr_col[p] = col[e];
    }
}

// ---------------------------------------------------------------------------
// Casts and weight composition
// ---------------------------------------------------------------------------
__global__ __launch_bounds__(256) void cast_x_kernel(const float* __restrict__ x,
                                                     unsigned short* __restrict__ xb, int n4) {
    int i = blockIdx.x * 256 + threadIdx.x;
    if (i < n4) {
        float4 v = ((const float4*)x)[i];
        ushort4 o;
        o.x = f2b(v.x); o.y = f2b(v.y); o.z = f2b(v.z); o.w = f2b(v.w);
        ((ushort4*)xb)[i] = o;
    }
}

// Wt[n][k] = bf16(W[k][n]) for W0, W1 (grid y selects)
__global__ __launch_bounds__(256) void cast_wt2_kernel(const float* __restrict__ Wa,
                                                       const float* __restrict__ Wb,
                                                       unsigned short* __restrict__ Ta,
                                                       unsigned short* __restrict__ Tb) {
    const float* W = blockIdx.y ? Wb : Wa;
    unsigned short* T = blockIdx.y ? Tb : Ta;
    int n = blockIdx.x, k = threadIdx.x;
    T[n * 256 + k] = f2b(W[k * 256 + n]);
}

__global__ __launch_bounds__(256) void cast_wt_kernel(const float* __restrict__ W,
                                                      unsigned short* __restrict__ Wt, int Ncol) {
    int n = blockIdx.x;
    int k = threadIdx.x;
    Wt[n * 256 + k] = f2b(W[k * Ncol + n]);
}

// WcT[n][k] = bf16( sum_m W[k][m] * Wn[m][n] )  — block = k, thread = n.
// W row k staged in LDS (coalesced); Wn[m][n] reads coalesced across threads.
__global__ __launch_bounds__(256) void compose_wc(const float* __restrict__ W0,
                                                  const float* __restrict__ Wn0,
                                                  const float* __restrict__ W1,
                                                  const float* __restrict__ Wn1,
                                                  unsigned short* __restrict__ T0,
                                                  unsigned short* __restrict__ T1) {
    const float* W  = blockIdx.y ? W1 : W0;
    const float* Wn = blockIdx.y ? Wn1 : Wn0;
    unsigned short* T = blockIdx.y ? T1 : T0;
    __shared__ float wrow[256];
    int k = blockIdx.x, n = threadIdx.x;
    wrow[n] = W[k * 256 + n];
    __syncthreads();
    float s = 0.f;
#pragma unroll 8
    for (int m = 0; m < 256; ++m) s = fmaf(wrow[m], Wn[m * 256 + n], s);
    T[n * 256 + k] = f2b(s);
}

// bc[n] = sum_m b[m]*Wn[m][n] + bn[n]  (fp32) — grid (1, 2)
__global__ __launch_bounds__(256) void compose_bc(const float* __restrict__ b0_,
                                                  const float* __restrict__ Wn0,
                                                  const float* __restrict__ bn0,
                                                  const float* __restrict__ b1_,
                                                  const float* __restrict__ Wn1,
                                                  const float* __restrict__ bn1,
                                                  float* __restrict__ bc0,
                                                  float* __restrict__ bc1) {
    const float* b  = blockIdx.y ? b1_ : b0_;
    const float* Wn = blockIdx.y ? Wn1 : Wn0;
    const float* bn = blockIdx.y ? bn1 : bn0;
    float* bc = blockIdx.y ? bc1 : bc0;
    int n = threadIdx.x;
    float s = bn[n];
    for (int m = 0; m < 256; ++m) s = fmaf(b[m], Wn[m * 256 + n], s);
    bc[n] = s;
}

// ---------------------------------------------------------------------------
// Dual-output bf16 MFMA GEMM: from one A[M x 256], compute
//   CH = A @ WtH^T + biasH   and   CC = A @ WtC^T + biasC
// A tile staged ONCE per K-step; 32 MFMA per K-step per wave.
// 128x128 tile, BK=32; coalesced LDS-staged epilogue for both outputs.
// ---------------------------------------------------------------------------
__global__ __launch_bounds__(256, 2) void dual_gemm_mfma(const unsigned short* __restrict__ A,
                                                         const unsigned short* __restrict__ WtH,
                                                         const unsigned short* __restrict__ WtC,
                                                         const float* __restrict__ biasH,
                                                         const float* __restrict__ biasC,
                                                         unsigned short* __restrict__ CH,
                                                         unsigned short* __restrict__ CC, int M) {
    __shared__ unsigned short smem[12288];  // Als 4096 | BlsH 4096 | BlsC 4096
    unsigned short* Als = smem;
    unsigned short* BlsH = smem + 4096;
    unsigned short* BlsC = smem + 8192;
    unsigned short* Cls = smem;  // epilogue alias: 128*72 = 9216

    int tid = threadIdx.x;
    int lane = tid & 63, wave = tid >> 6;
    int rowBase = blockIdx.x * 128, colBase = blockIdx.y * 128;

    float4v accH[4][4], accC[4][4];
#pragma unroll
    for (int i = 0; i < 4; ++i)
#pragma unroll
        for (int j = 0; j < 4; ++j) {
            accH[i][j] = (float4v){0.f, 0.f, 0.f, 0.f};
            accC[i][j] = (float4v){0.f, 0.f, 0.f, 0.f};
        }

    int wm = (wave & 1) * 64, wn = (wave >> 1) * 64;
    int sRow = wave * 32 + (lane >> 2);
    int sK = (lane & 3) * 8;
    int fr = lane & 15, fk = (lane >> 4) * 8;

    for (int k0 = 0; k0 < 256; k0 += 32) {
        int r0 = rowBase + sRow;       if (r0 >= M) r0 = M - 1;
        int r1 = rowBase + sRow + 16;  if (r1 >= M) r1 = M - 1;
        __builtin_amdgcn_global_load_lds((const AS1 void*)(A + (size_t)r0 * 256 + k0 + sK),
                                         (AS3 void*)&Als[(wave * 32) * 32], 16, 0, 0);
        __builtin_amdgcn_global_load_lds((const AS1 void*)(A + (size_t)r1 * 256 + k0 + sK),
                                         (AS3 void*)&Als[(wave * 32 + 16) * 32], 16, 0, 0);
        __builtin_amdgcn_global_load_lds((const AS1 void*)(WtH + (size_t)(colBase + sRow) * 256 + k0 + sK),
                                         (AS3 void*)&BlsH[(wave * 32) * 32], 16, 0, 0);
        __builtin_amdgcn_global_load_lds((const AS1 void*)(WtH + (size_t)(colBase + sRow + 16) * 256 + k0 + sK),
                                         (AS3 void*)&BlsH[(wave * 32 + 16) * 32], 16, 0, 0);
        __builtin_amdgcn_global_load_lds((const AS1 void*)(WtC + (size_t)(colBase + sRow) * 256 + k0 + sK),
                                         (AS3 void*)&BlsC[(wave * 32) * 32], 16, 0, 0);
        __builtin_amdgcn_global_load_lds((const AS1 void*)(WtC + (size_t)(colBase + sRow + 16) * 256 + k0 + sK),
                                         (AS3 void*)&BlsC[(wave * 32 + 16) * 32], 16, 0, 0);
        __syncthreads();

        short8 af[4], bh[4], bc[4];
#pragma unroll
        for (int i = 0; i < 4; ++i)
            af[i] = *(const short8*)&Als[(wm + i * 16 + fr) * 32 + fk];
#pragma unroll
        for (int j = 0; j < 4; ++j) {
            bh[j] = *(const short8*)&BlsH[(wn + j * 16 + fr) * 32 + fk];
            bc[j] = *(const short8*)&BlsC[(wn + j * 16 + fr) * 32 + fk];
        }
#pragma unroll
        for (int i = 0; i < 4; ++i)
#pragma unroll
            for (int j = 0; j < 4; ++j) {
                accH[i][j] = __builtin_amdgcn_mfma_f32_16x16x32_bf16(af[i], bh[j], accH[i][j], 0, 0, 0);
                accC[i][j] = __builtin_amdgcn_mfma_f32_16x16x32_bf16(af[i], bc[j], accC[i][j], 0, 0, 0);
            }
        __syncthreads();
    }

    // Epilogue x2 outputs: stage 128x64 halves (stride 72), coalesced 16B stores.
    int cr = (lane >> 4) * 4, cc = lane & 15;
    int myHalf = wave >> 1;
#pragma unroll
    for (int which = 0; which < 2; ++which) {
        const float* bias = which ? biasC : biasH;
        unsigned short* C = which ? CC : CH;
        float4v (*acc)[4] = which ? accC : accH;
#pragma unroll
        for (int jh = 0; jh < 2; ++jh) {
            if (myHalf == jh) {
#pragma unroll
                for (int j = 0; j < 4; ++j) {
                    float bv = bias[colBase + jh * 64 + j * 16 + cc];
#pragma unroll
                    for (int i = 0; i < 4; ++i) {
#pragma unroll
                        for (int r = 0; r < 4; ++r) {
                            Cls[(wm + i * 16 + cr + r) * 72 + j * 16 + cc] = f2b(acc[i][j][r] + bv);
                        }
                    }
                }
            }
            __syncthreads();
#pragma unroll
            for (int c = 0; c < 4; ++c) {
                int chunk = c * 256 + tid;
                int rw = chunk >> 3, off = (chunk & 7) * 8;
                int gr = rowBase + rw;
                if (gr < M) {
                    short8 val = *(const short8*)&Cls[rw * 72 + off];
                    *(short8*)&C[(size_t)gr * 256 + colBase + jh * 64 + off] = val;
                }
            }
            __syncthreads();
        }
    }
}

// ---------------------------------------------------------------------------
// Fused APPNP agg + residual + L2-norm + ReLU. One WAVE per node.
// Lane = 4 features (uint2 = 8B gather). 8-wide unrolled gather loop.
// ---------------------------------------------------------------------------
__global__ __launch_bounds__(256) void agg_norm_relu(const unsigned short* __restrict__ h0,
                                                     const unsigned short* __restrict__ nb,
                                                     const float* __restrict__ dinv,
                                                     const int* __restrict__ row_ptr,
                                                     const int* __restrict__ csr_col,
                                                     unsigned short* __restrict__ outp) {
    int wave = threadIdx.x >> 6, lane = threadIdx.x & 63;
    int v = blockIdx.x * 4 + wave;
    float dv = dinv[v];
    const uint2* nb2 = (const uint2*)nb;
    int base2 = v * 64 + lane;  // uint2 index of this lane's 4 features
    uint2 nbu = nb2[base2];
    float nbv0 = lo16f(nbu.x), nbv1 = hi16f(nbu.x);
    float nbv2 = lo16f(nbu.y), nbv3 = hi16f(nbu.y);
    float a0 = dv * nbv0, a1 = dv * nbv1, a2 = dv * nbv2, a3 = dv * nbv3;

    int s = row_ptr[v], e = row_ptr[v + 1];
    for (int b0 = s; b0 < e; b0 += 64) {
        int mm = e - b0;
        if (mm > 64) mm = 64;
        int c = 0;
        float dc = 0.f;
        if (lane < mm) { c = csr_col[b0 + lane]; dc = dinv[c]; }
        int mm8 = (mm + 7) & ~7;  // padded lanes: c=0, dc=0 (row 0 stays L1-hot)
        for (int j = 0; j < mm8; j += 8) {
            int ci[8];
            float di[8];
            uint2 u[8];
#pragma unroll
            for (int q = 0; q < 8; ++q) {
                ci[q] = __shfl(c, j + q);
                di[q] = __shfl(dc, j + q);
            }
#pragma unroll
            for (int q = 0; q < 8; ++q) u[q] = nb2[ci[q] * 64 + lane];
#pragma unroll
            for (int q = 0; q < 8; ++q) {
                a0 = fmaf(di[q], lo16f(u[q].x), a0);
                a1 = fmaf(di[q], hi16f(u[q].x), a1);
                a2 = fmaf(di[q], lo16f(u[q].y), a2);
                a3 = fmaf(di[q], hi16f(u[q].y), a3);
            }
        }
    }
    uint2 hu = ((const uint2*)h0)[base2];
    float v0 = lo16f(hu.x) + 0.5f * dv * a0 + 0.5f * nbv0;
    float v1 = hi16f(hu.x) + 0.5f * dv * a1 + 0.5f * nbv1;
    float v2 = lo16f(hu.y) + 0.5f * dv * a2 + 0.5f * nbv2;
    float v3 = hi16f(hu.y) + 0.5f * dv * a3 + 0.5f * nbv3;
    float ss = v0 * v0 + v1 * v1 + v2 * v2 + v3 * v3;
#pragma unroll
    for (int o = 32; o > 0; o >>= 1) ss += __shfl_xor(ss, o);
    float inv = 1.0f / fmaxf(sqrtf(ss), 1e-12f);
    ushort4 o;
    o.x = f2b(fmaxf(v0 * inv, 0.f));
    o.y = f2b(fmaxf(v1 * inv, 0.f));
    o.z = f2b(fmaxf(v2 * inv, 0.f));
    o.w = f2b(fmaxf(v3 * inv, 0.f));
    *(ushort4*)(outp + (size_t)v * 256 + lane * 4) = o;
}

// ---------------------------------------------------------------------------
// Final projection (MFMA): out[M x 32](fp32) = A[M x 256](bf16) @ W2 + b2
// ---------------------------------------------------------------------------
__global__ __launch_bounds__(256) void gemm_final_mfma(const unsigned short* __restrict__ A,
                                                       const unsigned short* __restrict__ Wt2,
                                                       const float* __restrict__ b2,
                                                       float* __restrict__ out, int M) {
    __shared__ unsigned short Als[128 * 32];
    __shared__ unsigned short Bls[32 * 32];
    int tid = threadIdx.x;
    int lane = tid & 63, wave = tid >> 6;
    int rowBase = blockIdx.x * 128;

    float4v acc[2][2];
#pragma unroll
    for (int i = 0; i < 2; ++i)
#pragma unroll
        for (int j = 0; j < 2; ++j) acc[i][j] = (float4v){0.f, 0.f, 0.f, 0.f};

    int sRow = wave * 32 + (lane >> 2);
    int sK = (lane & 3) * 8;
    int fr = lane & 15, fk = (lane >> 4) * 8;
    int bn = tid >> 3, bk4 = (tid & 7) * 4;

    for (int k0 = 0; k0 < 256; k0 += 32) {
        int r0 = rowBase + sRow;       if (r0 >= M) r0 = M - 1;
        int r1 = rowBase + sRow + 16;  if (r1 >= M) r1 = M - 1;
        __builtin_amdgcn_global_load_lds((const AS1 void*)(A + (size_t)r0 * 256 + k0 + sK),
                                         (AS3 void*)&Als[(wave * 32) * 32], 16, 0, 0);
        __builtin_amdgcn_global_load_lds((const AS1 void*)(A + (size_t)r1 * 256 + k0 + sK),
                                         (AS3 void*)&Als[(wave * 32 + 16) * 32], 16, 0, 0);
        *(ushort4*)&Bls[bn * 32 + bk4] = *(const ushort4*)&Wt2[bn * 256 + k0 + bk4];
        __syncthreads();

        short8 af[2], bfr[2];
#pragma unroll
        for (int i = 0; i < 2; ++i)
            af[i] = *(const short8*)&Als[(wave * 32 + i * 16 + fr) * 32 + fk];
#pragma unroll
        for (int j = 0; j < 2; ++j)
            bfr[j] = *(const short8*)&Bls[(j * 16 + fr) * 32 + fk];
#pragma unroll
        for (int i = 0; i < 2; ++i)
#pragma unroll
            for (int j = 0; j < 2; ++j)
                acc[i][j] = __builtin_amdgcn_mfma_f32_16x16x32_bf16(af[i], bfr[j], acc[i][j], 0, 0, 0);
        __syncthreads();
    }

    int cr = (lane >> 4) * 4, cc = lane & 15;
#pragma unroll
    for (int i = 0; i < 2; ++i) {
#pragma unroll
        for (int j = 0; j < 2; ++j) {
            int colg = j * 16 + cc;
            float bv = b2[colg];
#pragma unroll
            for (int r = 0; r < 4; ++r) {
                int rowg = rowBase + wave * 32 + i * 16 + cr + r;
                if (rowg < M) out[(size_t)rowg * 32 + colg] = acc[i][j][r] + bv;
            }
        }
    }
}

// ---------------------------------------------------------------------------
extern "C" void kernel_launch(void* const* d_in, const int* in_sizes, int n_in,
                              void* d_out, int out_size, void* d_ws, size_t ws_size,
                              hipStream_t stream) {
    const float* x   = (const float*)d_in[0];
    const int* edge  = (const int*)d_in[1];
    const float* W0  = (const float*)d_in[2];
    const float* b0  = (const float*)d_in[3];
    const float* Wn0 = (const float*)d_in[4];
    const float* bn0 = (const float*)d_in[5];
    const float* W1  = (const float*)d_in[6];
    const float* b1  = (const float*)d_in[7];
    const float* Wn1 = (const float*)d_in[8];
    const float* bn1 = (const float*)d_in[9];
    const float* W2  = (const float*)d_in[10];
    const float* b2  = (const float*)d_in[11];
    float* out = (float*)d_out;

    const int N = NN, E = NE;
    const int* row = edge;
    const int* col = edge + E;

    // Workspace layout
    char* p = (char*)d_ws;
    unsigned short* Xbf = (unsigned short*)p; p += (size_t)N * DD * 2;
    unsigned short* Abf = (unsigned short*)p; p += (size_t)N * DD * 2;
    unsigned short* Bbf = (unsigned short*)p; p += (size_t)N * DD * 2;
    unsigned short* Wt0  = (unsigned short*)p; p += 256 * 256 * 2;
    unsigned short* Wt1  = (unsigned short*)p; p += 256 * 256 * 2;
    unsigned short* WcT0 = (unsigned short*)p; p += 256 * 256 * 2;
    unsigned short* WcT1 = (unsigned short*)p; p += 256 * 256 * 2;
    unsigned short* Wt2  = (unsigned short*)p; p += 32 * 256 * 2;
    float* bc0   = (float*)p; p += 256 * 4;
    float* bc1   = (float*)p; p += 256 * 4;
    int* cnt     = (int*)p; p += (size_t)N * 4;
    int* row_ptr = (int*)p; p += (size_t)(N + 1) * 4;
    int* cursor  = (int*)p; p += (size_t)N * 4;
    float* dinv  = (float*)p; p += (size_t)N * 4;
    int* csr_col = (int*)p; p += (size_t)E * 4;
    int* bsum    = (int*)p; p += 256 * 4;
    int* bpre    = (int*)p; p += 256 * 4;

    const int nblk = (N + 255) / 256;  // 196
    const int eb = (E + 255) / 256;

    // CSR build
    hipMemsetAsync(cnt, 0, (size_t)N * sizeof(int), stream);
    count_kernel<<<eb, 256, 0, stream>>>(row, cnt, E);
    block_sums<<<nblk, 256, 0, stream>>>(cnt, bsum, N);
    scan_bsums<<<1, 256, 0, stream>>>(bsum, bpre, nblk);
    fill_rowptr<<<nblk, 256, 0, stream>>>(cnt, bpre, row_ptr, cursor, dinv, N, E);
    scatter_kernel<<<eb, 256, 0, stream>>>(row, col, cursor, csr_col, E);

    // casts + weight composition: Wc = W @ Wn, bc = b @ Wn + bn
    cast_x_kernel<<<(N * DD / 4 + 255) / 256, 256, 0, stream>>>(x, Xbf, N * DD / 4);
    cast_wt2_kernel<<<dim3(256, 2), 256, 0, stream>>>(W0, W1, Wt0, Wt1);
    compose_wc<<<dim3(256, 2), 256, 0, stream>>>(W0, Wn0, W1, Wn1, WcT0, WcT1);
    compose_bc<<<dim3(1, 2), 256, 0, stream>>>(b0, Wn0, bn0, b1, Wn1, bn1, bc0, bc1);
    cast_wt_kernel<<<32, 256, 0, stream>>>(W2, Wt2, 32);

    dim3 g((N + 127) / 128, 2);  // 391 x 2
    // Layer 1: h -> Abf, nb -> Bbf (independent via composite weight), agg -> Abf
    dual_gemm_mfma<<<g, 256, 0, stream>>>(Xbf, Wt0, WcT0, b0, bc0, Abf, Bbf, N);
    agg_norm_relu<<<N / 4, 256, 0, stream>>>(Abf, Bbf, dinv, row_ptr, csr_col, Abf);
    // Layer 2: h -> Bbf, nb -> Xbf, agg -> Bbf
    dual_gemm_mfma<<<g, 256, 0, stream>>>(Abf, Wt1, WcT1, b1, bc1, Bbf, Xbf, N);
    agg_norm_relu<<<N / 4, 256, 0, stream>>>(Bbf, Xbf, dinv, row_ptr, csr_col, Bbf);
    // Final projection
    gemm_final_mfma<<<(N + 127) / 128, 256, 0, stream>>>(Bbf, Wt2, b2, out, N);
}